// Round 6
// baseline (351.704 us; speedup 1.0000x reference)
//
#include <hip/hip_runtime.h>
#include <hip/hip_bf16.h>
#include <stdint.h>

typedef __bf16 bf16_t;
typedef _Float16 f16_t;
typedef _Float16 f16x8 __attribute__((ext_vector_type(8)));
typedef _Float16 f16x4 __attribute__((ext_vector_type(4)));
typedef float f32x4 __attribute__((ext_vector_type(4)));

#define HID 512
#define NRAW 736      // 32 * 23 (source layout)
#define NRAW_PAD 768  // 32 * 24 (channel-aligned: 23 coeffs + 1 zero pad)
#define TAILB 3.0f

__device__ __forceinline__ void glds16(const void* g, void* s) {
  __builtin_amdgcn_global_load_lds(
      (const __attribute__((address_space(1))) void*)g,
      (__attribute__((address_space(3))) void*)s, 16, 0, 0);
}
__device__ __forceinline__ float frcp(float x) { return __builtin_amdgcn_rcpf(x); }

// ---------------------------------------------------------------------------
__global__ void detect_dtype(const void* x, int* flag) {
  __shared__ int s;
  if (threadIdx.x == 0) s = 0;
  __syncthreads();
  const bf16_t* xb = (const bf16_t*)x;
  int cnt = 0;
  for (int j = 0; j < 16; j++) {
    float v = (float)xb[threadIdx.x * 16 + j];
    if (!(v == v) || fabsf(v) > 64.0f) cnt++;
  }
  atomicAdd(&s, cnt);
  __syncthreads();
  if (threadIdx.x == 0) *flag = (s > 64) ? 1 : 0;
}

// ---------------------------------------------------------------------------
__global__ void conv_wb(const void* W1, const void* W2, const void* W3,
                        const void* b1, const void* b2, const void* b3,
                        f16_t* __restrict__ w1t, f16_t* __restrict__ w2t,
                        f16_t* __restrict__ w3t,
                        float* __restrict__ bf1, float* __restrict__ bf2,
                        float* __restrict__ bf3, const int* flagp) {
  const int flag = *flagp;
  auto rd = [&](const void* p, size_t idx) -> float {
    return flag ? ((const float*)p)[idx] : (float)((const bf16_t*)p)[idx];
  };
  int i = blockIdx.x * 256 + threadIdx.x;
  if (i < 512 * 32)  { w1t[i] = (f16_t)rd(W1, (size_t)(i & 31) * 512 + (i >> 5)); return; }
  i -= 512 * 32;
  if (i < 512 * 512) { w2t[i] = (f16_t)rd(W2, (size_t)(i & 511) * 512 + (i >> 9)); return; }
  i -= 512 * 512;
  if (i < NRAW_PAD * 512) {
    int n = i >> 9, k = i & 511;
    int ch = n / 24, e = n % 24;
    w3t[i] = (e < 23) ? (f16_t)rd(W3, (size_t)k * NRAW + ch * 23 + e) : (f16_t)0.0f;
    return;
  }
  i -= NRAW_PAD * 512;
  if (i < 512) { bf1[i] = rd(b1, i); return; }
  i -= 512;
  if (i < 512) { bf2[i] = rd(b2, i); return; }
  i -= 512;
  if (i < NRAW_PAD) {
    int ch = i / 24, e = i % 24;
    bf3[i] = (e < 23) ? rd(b3, (size_t)ch * 23 + e) : 0.0f;
  }
}

__global__ void ld_finalize(const float* __restrict__ ldp, void* __restrict__ outv,
                            const int* __restrict__ flagp, int M) {
  const int i = blockIdx.x * 256 + threadIdx.x;
  if (i >= M) return;
  float s = 0.f;
  #pragma unroll
  for (int n = 0; n < 4; n++) s += ldp[(size_t)n * M + i];
  if (*flagp) ((float*)outv)[(size_t)M * 64 + i] = s;
  else        ((bf16_t*)outv)[(size_t)M * 64 + i] = (bf16_t)s;
}

// ---------------------------------------------------------------------------
// Fused GEMM1+GEMM2: round-4 structure with two targeted fixes:
//   (1) Bs double-buffered (+16 KB -> 48 KB LDS, still 3 blocks/CU);
//   (2) glds16 issued right AFTER the publishing barrier, with GEMM2's
//       32 MFMA + GEMM1's 8 MFMA as latency cover before the next drain
//       (round-4 issued at top-of-iter and drained after only ~8 MFMA).
//   2 barriers/iter (was 3). As discipline identical to the verified
//   round-4 scheme: GEMM2 reads As(tile k) -> barrier-1 -> ds_write
//   As(tile k+1) -> barrier-2 (publish). Bs[nb] (staged) vs Bs[cur]
//   (read) are disjoint; barrier-1's implicit vmcnt(0) publishes Bs[nb].
// ---------------------------------------------------------------------------
__launch_bounds__(256)
__global__ void gemm12(const void* __restrict__ xorig, const f16_t* __restrict__ W1t,
                       const float* __restrict__ b1, const f16_t* __restrict__ W2t,
                       const float* __restrict__ b2, f16_t* __restrict__ H2,
                       int r0, const int* __restrict__ flagp) {
  constexpr int BK = 64;
  constexpr int BUF = 128 * BK;  // 8192 f16 per Bs buffer
  __shared__ __align__(16) f16_t As[BUF], Bs[2 * BUF];  // 16 + 32 = 48 KB
  const int t = threadIdx.x;
  const int id = blockIdx.x;
  const int xcd = id & 7, s = id >> 3;
  const int n0 = (s & 3) * 128;
  const int m0 = ((s >> 2) * 8 + xcd) * 128;
  const int lrow = t >> 3, lcb = t & 7;
  const int lane = t & 63, w = t >> 6;
  const int wr = (w >> 1) * 64, wc = (w & 1) * 64, wc2 = (w & 1) * 32;
  const int lm = lane & 15, quad = lane >> 4;
  const int flag = *flagp;

  // W2t staging (pre-swizzled global col, linear LDS dest; dbuf offset at use)
  const f16_t* gb[4];
  f16_t* ldb[4];
  #pragma unroll
  for (int r = 0; r < 4; r++) {
    const int row = r * 32 + lrow;
    const int gc = (lcb ^ (row & 7)) * 8;
    gb[r] = W2t + (size_t)(n0 + row) * 512 + gc;
    ldb[r] = &Bs[row * BK + lcb * 8];
  }
  // GEMM2 fragment read offsets (As direct; Bs + cur*BUF at use)
  int apo[4][2], bpo[4][2];
  #pragma unroll
  for (int i = 0; i < 4; i++) {
    const int ra = wr + i * 16 + lm, rb = wc + i * 16 + lm;
    #pragma unroll
    for (int ksi = 0; ksi < 2; ksi++) {
      const int qb = ksi * 4 + quad;
      apo[i][ksi] = ra * BK + ((qb ^ (ra & 7)) << 3);
      bpo[i][ksi] = rb * BK + ((qb ^ (rb & 7)) << 3);
    }
  }
  // X fragments (B operand of h-mfma)
  f16x8 xfr[4];
  #pragma unroll
  for (int i = 0; i < 4; i++) {
    const size_t xrow = (size_t)(r0 + m0 + wr + i * 16 + lm);
    if (flag) {
      const float* px = (const float*)xorig + xrow * 64 + quad * 8;
      const float4 a = *(const float4*)px;
      const float4 b = *(const float4*)(px + 4);
      f16x8 v;
      v[0] = (f16_t)a.x; v[1] = (f16_t)a.y; v[2] = (f16_t)a.z; v[3] = (f16_t)a.w;
      v[4] = (f16_t)b.x; v[5] = (f16_t)b.y; v[6] = (f16_t)b.z; v[7] = (f16_t)b.w;
      xfr[i] = v;
    } else {
      const bf16_t* px = (const bf16_t*)xorig + xrow * 64 + quad * 8;
      f16x8 v;
      #pragma unroll
      for (int j = 0; j < 8; j++) v[j] = (f16_t)(float)px[j];
      xfr[i] = v;
    }
  }
  // W1 A-frag pointers + bias pointers
  const f16_t* w1p0 = W1t + (size_t)(wc2 + lm) * 32 + quad * 8;
  const f16_t* w1p1 = W1t + (size_t)(wc2 + 16 + lm) * 32 + quad * 8;
  const float* b1p0 = b1 + wc2 + 4 * quad;
  const float* b1p1 = b1 + wc2 + 16 + 4 * quad;
  // As write offsets (k0-invariant)
  int woff[4][2];
  #pragma unroll
  for (int i = 0; i < 4; i++) {
    const int row = wr + i * 16 + lm;
    #pragma unroll
    for (int Tl = 0; Tl < 2; Tl++) {
      const int cb = (wc2 >> 3) + 2 * Tl + (quad >> 1);
      woff[i][Tl] = row * BK + ((cb ^ (row & 7)) << 3) + 4 * (quad & 1);
    }
  }

  f32x4 acc[4][4] = {};

  // ---- prologue: h(0) -> As; stage Bs[0]; preload W1/bias for h(1) ----
  {
    f16x8 w1f0 = *(const f16x8*)w1p0;
    f16x8 w1f1 = *(const f16x8*)w1p1;
    const float4 bv0 = *(const float4*)b1p0;
    const float4 bv1 = *(const float4*)b1p1;
    #pragma unroll
    for (int r = 0; r < 4; r++) glds16(gb[r], ldb[r]);
    #pragma unroll
    for (int i = 0; i < 4; i++) {
      f32x4 z = {};
      const f32x4 h0 = __builtin_amdgcn_mfma_f32_16x16x32_f16(w1f0, xfr[i], z, 0, 0, 0);
      const f32x4 h1 = __builtin_amdgcn_mfma_f32_16x16x32_f16(w1f1, xfr[i], z, 0, 0, 0);
      f16x4 v0, v1;
      v0[0] = (f16_t)fmaxf(h0[0] + bv0.x, 0.0f);
      v0[1] = (f16_t)fmaxf(h0[1] + bv0.y, 0.0f);
      v0[2] = (f16_t)fmaxf(h0[2] + bv0.z, 0.0f);
      v0[3] = (f16_t)fmaxf(h0[3] + bv0.w, 0.0f);
      v1[0] = (f16_t)fmaxf(h1[0] + bv1.x, 0.0f);
      v1[1] = (f16_t)fmaxf(h1[1] + bv1.y, 0.0f);
      v1[2] = (f16_t)fmaxf(h1[2] + bv1.z, 0.0f);
      v1[3] = (f16_t)fmaxf(h1[3] + bv1.w, 0.0f);
      *(f16x4*)&As[woff[i][0]] = v0;
      *(f16x4*)&As[woff[i][1]] = v1;
    }
  }
  // frags/bias for h(1), consumed at iter 0
  f16x8 w1fa = *(const f16x8*)(w1p0 + (size_t)64 * 32);
  f16x8 w1fb = *(const f16x8*)(w1p1 + (size_t)64 * 32);
  float4 bva = *(const float4*)(b1p0 + 64);
  float4 bvb = *(const float4*)(b1p1 + 64);
  __syncthreads();  // publish As(0) + drain Bs[0] (one-time uncovered drain)

  #pragma unroll
  for (int k = 0; k < 8; k++) {
    const int cur = k & 1, nb = cur ^ 1;
    // issue Bs[nb] staging for tile k+1 NOW: GEMM2+GEMM1 below are the cover
    if (k < 7) {
      #pragma unroll
      for (int r = 0; r < 4; r++)
        glds16(gb[r] + (k + 1) * 64, ldb[r] + nb * BUF);
    }
    // GEMM2 on (As, Bs[cur]) -- 32 MFMA
    #pragma unroll
    for (int ksi = 0; ksi < 2; ksi++) {
      f16x8 af[4], bf[4];
      #pragma unroll
      for (int i = 0; i < 4; i++) af[i] = *(const f16x8*)&As[apo[i][ksi]];
      #pragma unroll
      for (int j = 0; j < 4; j++) bf[j] = *(const f16x8*)&Bs[cur * BUF + bpo[j][ksi]];
      __builtin_amdgcn_s_setprio(1);
      #pragma unroll
      for (int i = 0; i < 4; i++)
        #pragma unroll
        for (int j = 0; j < 4; j++)
          acc[i][j] = __builtin_amdgcn_mfma_f32_16x16x32_f16(af[i], bf[j], acc[i][j], 0, 0, 0);
      __builtin_amdgcn_s_setprio(0);
    }
    if (k < 7) {
      // GEMM1: h(k+1) in regs (more cover for the in-flight Bs[nb] loads)
      f32x4 h[4][2];
      #pragma unroll
      for (int i = 0; i < 4; i++) {
        f32x4 z = {};
        h[i][0] = __builtin_amdgcn_mfma_f32_16x16x32_f16(w1fa, xfr[i], z, 0, 0, 0);
        h[i][1] = __builtin_amdgcn_mfma_f32_16x16x32_f16(w1fb, xfr[i], z, 0, 0, 0);
      }
      __syncthreads();  // barrier-1: ends this iter's As/Bs readers;
                        // implicit vmcnt(0) publishes Bs[nb] (covered above)
      #pragma unroll
      for (int i = 0; i < 4; i++) {
        f16x4 v0, v1;
        v0[0] = (f16_t)fmaxf(h[i][0][0] + bva.x, 0.0f);
        v0[1] = (f16_t)fmaxf(h[i][0][1] + bva.y, 0.0f);
        v0[2] = (f16_t)fmaxf(h[i][0][2] + bva.z, 0.0f);
        v0[3] = (f16_t)fmaxf(h[i][0][3] + bva.w, 0.0f);
        v1[0] = (f16_t)fmaxf(h[i][1][0] + bvb.x, 0.0f);
        v1[1] = (f16_t)fmaxf(h[i][1][1] + bvb.y, 0.0f);
        v1[2] = (f16_t)fmaxf(h[i][1][2] + bvb.z, 0.0f);
        v1[3] = (f16_t)fmaxf(h[i][1][3] + bvb.w, 0.0f);
        *(f16x4*)&As[woff[i][0]] = v0;
        *(f16x4*)&As[woff[i][1]] = v1;
      }
      if (k < 6) {  // prefetch W1/bias for h(k+2), consumed next iter
        w1fa = *(const f16x8*)(w1p0 + (size_t)(k + 2) * 64 * 32);
        w1fb = *(const f16x8*)(w1p1 + (size_t)(k + 2) * 64 * 32);
        bva = *(const float4*)(b1p0 + (k + 2) * 64);
        bvb = *(const float4*)(b1p1 + (k + 2) * 64);
      }
      __syncthreads();  // barrier-2: publish As(k+1)
    }
  }
  #pragma unroll
  for (int i = 0; i < 4; i++)
    #pragma unroll
    for (int j = 0; j < 4; j++) {
      const int col = n0 + wc + j * 16 + lm;
      const float bv = b2[col];
      #pragma unroll
      for (int r = 0; r < 4; r++) {
        const int rowi = m0 + wr + i * 16 + quad * 4 + r;
        H2[(size_t)rowi * HID + col] = (f16_t)fmaxf(acc[i][j][r] + bv, 0.0f);
      }
    }
}

// ---------------------------------------------------------------------------
// Fused GEMM3 + spline (verified round 4) + folded-in masked passthrough
// (replaces the convert_x kernel: each block copies its 128 rows x its
// ntile's 8 passthrough columns -> exactly covers out[:, :32] grid-wide).
// ---------------------------------------------------------------------------
#define RSH 200        // rawh stride (f16)
#define SP1 0.5413248546f  // softplus(SP1) == 1

__launch_bounds__(512, 4)
__global__ void gemm3_spline(const f16_t* __restrict__ A, const f16_t* __restrict__ Bt,
                             const float* __restrict__ bias,
                             const void* __restrict__ xorig,
                             void* __restrict__ outv, float* __restrict__ ldp,
                             int M, int r0, const int* __restrict__ flagp) {
  // As dbuf: 2 x 128x64, Bs dbuf: 2 x 192x64 (f16) -> 81920 B total.
  __shared__ __align__(16) f16_t lds[2 * 8192 + 2 * 12288];
  f16_t* As = lds;
  f16_t* Bs = lds + 2 * 8192;
  f16_t* rawh = lds;  // 128*200 = 25600 f16 (aliases staging, post-loop)

  const int t = threadIdx.x;          // 0..511
  const int id = blockIdx.x;
  const int xcd = id & 7, sloc = id >> 3;
  const int cpx = gridDim.x >> 3;     // grid % 8 == 0 guaranteed by launcher
  const int wg = xcd * cpx + sloc;    // bijective XCD swizzle
  const int ntile = wg & 3;           // 4 N-tiles of 192 (8 channels each)
  const int m0 = (wg >> 2) * 128;
  const int n0 = ntile * 192;
  const int lane = t & 63, w = t >> 6;
  const int lm = lane & 15, quad = lane >> 4;
  const int wrow = (w >> 2) * 64, wcol = (w & 3) * 48;  // 2M x 4N wave grid
  const int lrow = t >> 3, lcb = t & 7;  // staging coords (64 rows x 8 chunks)
  const int flag = *flagp;

  // ---- staging: pre-swizzled global src, linear (swizzle-slot) LDS dest ----
  const int gc = (lcb ^ (lrow & 7)) * 8;
  const f16_t* gA = A + (size_t)(m0 + lrow) * 512 + gc;
  const f16_t* gB = Bt + (size_t)(n0 + lrow) * 512 + gc;
  f16_t* ldA = As + lrow * 64 + lcb * 8;   // rows lrow + r*64, r<2
  f16_t* ldB = Bs + lrow * 64 + lcb * 8;   // rows lrow + r*64, r<3

  // ---- fragment read offsets (elements; ksi=1 toggles ^32) ----
  int aoff[4], boff[3];
  #pragma unroll
  for (int i = 0; i < 4; i++) {
    const int ra = wrow + i * 16 + lm;
    aoff[i] = ra * 64 + ((quad ^ (ra & 7)) << 3);
  }
  #pragma unroll
  for (int j = 0; j < 3; j++) {
    const int rb = wcol + j * 16 + lm;
    boff[j] = rb * 64 + ((quad ^ (rb & 7)) << 3);
  }

  // spline inputs + bias (register prefetch, no LDS interaction)
  const int prow = t >> 3, pch = t & 7;
  float xt_pre[2];
  #pragma unroll
  for (int e = 0; e < 2; e++) {
    const size_t gi = (size_t)(r0 + m0 + e * 64 + prow) * 64 + 32 + ntile * 8 + pch;
    xt_pre[e] = flag ? ((const float*)xorig)[gi] : (float)((const bf16_t*)xorig)[gi];
  }
  float bv3[3];
  #pragma unroll
  for (int j = 0; j < 3; j++) bv3[j] = bias[n0 + wcol + j * 16 + lm];

  // ---- masked passthrough (was convert_x): this block's 128 rows, cols
  // [ntile*8, ntile*8+8) of the x[:, :32] region; grid covers all (row,col).
  if (t < 128) {
    const size_t base = (size_t)(r0 + m0 + t) * 64 + ntile * 8;
    if (flag) {
      const float4* s4 = (const float4*)((const float*)xorig + base);
      float4* d4 = (float4*)((float*)outv + base);
      d4[0] = s4[0]; d4[1] = s4[1];
    } else {
      *(uint4*)((bf16_t*)outv + base) = *(const uint4*)((const bf16_t*)xorig + base);
    }
  }

  // ---- prologue: stage tile 0 into buf 0 ----
  #pragma unroll
  for (int r = 0; r < 2; r++) glds16(gA + r * 32768, ldA + r * 4096);
  #pragma unroll
  for (int r = 0; r < 3; r++) glds16(gB + r * 32768, ldB + r * 4096);
  __syncthreads();

  f32x4 acc[4][3] = {};

  #pragma unroll
  for (int t8 = 0; t8 < 8; t8++) {
    const f16_t* Ab = As + (t8 & 1) * 8192;
    const f16_t* Bb = Bs + (t8 & 1) * 12288;
    // issue next tile's staging EARLY -- the rest of this tile's ds_read +
    // MFMA covers the load latency; drained by the tile-end __syncthreads.
    if (t8 < 7) {
      const int nb = (t8 + 1) & 1;
      #pragma unroll
      for (int r = 0; r < 2; r++)
        glds16(gA + r * 32768 + (t8 + 1) * 64, ldA + nb * 8192 + r * 4096);
      #pragma unroll
      for (int r = 0; r < 3; r++)
        glds16(gB + r * 32768 + (t8 + 1) * 64, ldB + nb * 12288 + r * 4096);
    }
    #pragma unroll
    for (int ksi = 0; ksi < 2; ksi++) {
      f16x8 af[4], bf[3];
      #pragma unroll
      for (int i = 0; i < 4; i++)
        af[i] = *(const f16x8*)(Ab + (aoff[i] ^ (ksi << 5)));
      #pragma unroll
      for (int j = 0; j < 3; j++)
        bf[j] = *(const f16x8*)(Bb + (boff[j] ^ (ksi << 5)));
      __builtin_amdgcn_s_setprio(1);
      #pragma unroll
      for (int i = 0; i < 4; i++)
        #pragma unroll
        for (int j = 0; j < 3; j++)
          acc[i][j] = __builtin_amdgcn_mfma_f32_16x16x32_f16(af[i], bf[j], acc[i][j], 0, 0, 0);
      __builtin_amdgcn_s_setprio(0);
    }
    __syncthreads();   // drains this wave's ds_reads + ALL glds16 (vmcnt 0);
                       // publishes buf^1 for next tile across all waves
  }

  // ---- epilogue: acc+bias -> rawh LDS (staging reads all done) ----
  #pragma unroll
  for (int i = 0; i < 4; i++)
    #pragma unroll
    for (int j = 0; j < 3; j++) {
      const int col = wcol + j * 16 + lm;
      #pragma unroll
      for (int r = 0; r < 4; r++)
        rawh[(wrow + i * 16 + quad * 4 + r) * RSH + col] = (f16_t)(acc[i][j][r] + bv3[j]);
    }
  __syncthreads();

  // ---- spline: 2 (row, channel) pairs per thread ----
  #pragma unroll
  for (int e = 0; e < 2; e++) {
    const int row = e * 64 + prow;
    const f16_t* c16 = &rawh[row * RSH + pch * 24];
    const f16x8 v0 = *(const f16x8*)(c16);
    const f16x8 v1 = *(const f16x8*)(c16 + 8);
    const f16x8 v2 = *(const f16x8*)(c16 + 16);
    float wa[8], ha[8], da[7];
    #pragma unroll
    for (int j = 0; j < 8; j++) { wa[j] = (float)v0[j]; ha[j] = (float)v1[j]; }
    #pragma unroll
    for (int j = 0; j < 7; j++) da[j] = (float)v2[j];

    const float xt = xt_pre[e];
    const bool inside = (xt >= -TAILB) && (xt <= TAILB);
    const float xc = fminf(fmaxf(xt, -TAILB + 1e-6f), TAILB - 1e-6f);

    float mw = wa[0], mh = ha[0];
    #pragma unroll
    for (int j = 1; j < 8; j++) { mw = fmaxf(mw, wa[j]); mh = fmaxf(mh, ha[j]); }
    float ew[8], eh[8], sew = 0.f, seh = 0.f;
    #pragma unroll
    for (int j = 0; j < 8; j++) {
      ew[j] = __expf(wa[j] - mw); sew += ew[j];
      eh[j] = __expf(ha[j] - mh); seh += eh[j];
    }
    const float wsc = 6.0f * frcp(sew), hsc = 6.0f * frcp(seh);
    #pragma unroll
    for (int j = 0; j < 8; j++) { ew[j] *= wsc; eh[j] *= hsc; }

    float accw = -TAILB, runh = -TAILB;
    float cwk = -TAILB, chk = -TAILB;
    float wk = ew[0], hk = eh[0];
    float dkr = SP1, dk1r = da[0];
    #pragma unroll
    for (int i = 0; i < 7; i++) {
      accw += ew[i];
      runh += eh[i];
      const bool cond = accw < xc;
      cwk  = cond ? accw : cwk;
      chk  = cond ? runh : chk;
      wk   = cond ? ew[i + 1] : wk;
      hk   = cond ? eh[i + 1] : hk;
      dkr  = cond ? da[i] : dkr;
      dk1r = cond ? ((i == 6) ? SP1 : da[i + 1]) : dk1r;
    }
    const float dk  = fmaxf(dkr, 0.0f)  + __logf(1.0f + __expf(-fabsf(dkr)));
    const float dk1 = fmaxf(dk1r, 0.0f) + __logf(1.0f + __expf(-fabsf(dk1r)));

    const float rwk = frcp(wk);
    float xi = (xc - cwk) * rwk;
    xi = fminf(fmaxf(xi, 1e-6f), 1.0f - 1e-6f);
    const float om = 1.0f - xi;
    const float sl = hk * rwk;
    const float num = hk * (sl * xi * xi + dk * xi * om);
    const float den = sl + (dk + dk1 - 2.0f * sl) * xi * om;
    const float y_in = chk + num * frcp(den);
    const float t1 = sl * sl * (dk1 * xi * xi + 2.0f * sl * xi * om + dk * om * om);
    const float ld_in = __logf(t1 + 1e-8f) - __logf(den * den + 1e-8f);

    const float yv = inside ? y_in : xt;
    const float ldv = inside ? ld_in : 0.0f;

    const size_t grow = (size_t)(r0 + m0 + row);
    if (flag) ((float*)outv)[grow * 64 + 32 + ntile * 8 + pch] = yv;
    else      ((bf16_t*)outv)[grow * 64 + 32 + ntile * 8 + pch] = (bf16_t)yv;

    float l = ldv + __shfl_down(ldv, 1, 8);
    l += __shfl_down(l, 2, 8);
    l += __shfl_down(l, 4, 8);
    if ((t & 7) == 0) ldp[(size_t)ntile * M + grow] = l;
  }
}

// ---------------------------------------------------------------------------
extern "C" void kernel_launch(void* const* d_in, const int* in_sizes, int n_in,
                              void* d_out, int out_size, void* d_ws, size_t ws_size,
                              hipStream_t stream) {
  const void* x  = d_in[0];
  const void* W1 = d_in[1];
  const void* b1 = d_in[2];
  const void* W2 = d_in[3];
  const void* b2 = d_in[4];
  const void* W3 = d_in[5];
  const void* b3 = d_in[6];
  const int M = in_sizes[0] / 64;  // 131072

  char* ws = (char*)d_ws;
  size_t off = 0;
  auto alloc = [&](size_t bytes) {
    void* p = ws + off;
    off += (bytes + 255) & ~(size_t)255;
    return p;
  };
  int*   flag = (int*)alloc(256);
  float* bf1  = (float*)alloc(512 * 4);
  float* bf2  = (float*)alloc(512 * 4);
  float* bf3  = (float*)alloc(NRAW_PAD * 4);
  f16_t* W1t  = (f16_t*)alloc((size_t)512 * 32 * 2);
  f16_t* W2t  = (f16_t*)alloc((size_t)512 * 512 * 2);
  f16_t* W3t  = (f16_t*)alloc((size_t)NRAW_PAD * 512 * 2);
  float* ldp  = (float*)alloc((size_t)8 * M * 4);

  const size_t per_row = (size_t)HID * 2;
  size_t avail = (ws_size > off + 4096) ? (ws_size - off - 4096) : 0;
  long rows = (long)(avail / per_row);
  rows -= rows % 1024;
  if (rows > M) rows = M;
  if (rows < 1024) rows = 1024;

  f16_t* h2 = (f16_t*)alloc((size_t)rows * HID * 2);

  detect_dtype<<<1, 256, 0, stream>>>(x, flag);
  conv_wb<<<2631, 256, 0, stream>>>(W1, W2, W3, b1, b2, b3,
                                    W1t, W2t, W3t, bf1, bf2, bf3, flag);

  for (int r0 = 0; r0 < M; r0 += (int)rows) {
    const int mc = (int)((M - r0 < rows) ? (M - r0) : rows);
    const int mt128 = mc / 128;
    gemm12<<<mt128 * 4, 256, 0, stream>>>(x, W1t, bf1, W2t, bf2, h2, r0, flag);
    gemm3_spline<<<mt128 * 4, 512, 0, stream>>>(
        h2, W3t, bf3, x, d_out, ldp, M, r0, flag);
  }
  ld_finalize<<<(M + 255) / 256, 256, 0, stream>>>(ldp, d_out, flag, M);
}

// Round 7
// 320.522 us; speedup vs baseline: 1.0973x; 1.0973x over previous
//
#include <hip/hip_runtime.h>
#include <hip/hip_bf16.h>
#include <stdint.h>

typedef __bf16 bf16_t;
typedef _Float16 f16_t;
typedef _Float16 f16x8 __attribute__((ext_vector_type(8)));
typedef _Float16 f16x4 __attribute__((ext_vector_type(4)));
typedef float f32x4 __attribute__((ext_vector_type(4)));

#define HID 512
#define NRAW 736      // 32 * 23 (source layout)
#define NRAW_PAD 768  // 32 * 24 (channel-aligned: 23 coeffs + 1 zero pad)
#define TAILB 3.0f

__device__ __forceinline__ void glds16(const void* g, void* s) {
  __builtin_amdgcn_global_load_lds(
      (const __attribute__((address_space(1))) void*)g,
      (__attribute__((address_space(3))) void*)s, 16, 0, 0);
}
__device__ __forceinline__ float frcp(float x) { return __builtin_amdgcn_rcpf(x); }

// ---------------------------------------------------------------------------
__global__ void detect_dtype(const void* x, int* flag) {
  __shared__ int s;
  if (threadIdx.x == 0) s = 0;
  __syncthreads();
  const bf16_t* xb = (const bf16_t*)x;
  int cnt = 0;
  for (int j = 0; j < 16; j++) {
    float v = (float)xb[threadIdx.x * 16 + j];
    if (!(v == v) || fabsf(v) > 64.0f) cnt++;
  }
  atomicAdd(&s, cnt);
  __syncthreads();
  if (threadIdx.x == 0) *flag = (s > 64) ? 1 : 0;
}

// ---------------------------------------------------------------------------
__global__ void conv_wb(const void* W1, const void* W2, const void* W3,
                        const void* b1, const void* b2, const void* b3,
                        f16_t* __restrict__ w1t, f16_t* __restrict__ w2t,
                        f16_t* __restrict__ w3t,
                        float* __restrict__ bf1, float* __restrict__ bf2,
                        float* __restrict__ bf3, const int* flagp) {
  const int flag = *flagp;
  auto rd = [&](const void* p, size_t idx) -> float {
    return flag ? ((const float*)p)[idx] : (float)((const bf16_t*)p)[idx];
  };
  int i = blockIdx.x * 256 + threadIdx.x;
  if (i < 512 * 32)  { w1t[i] = (f16_t)rd(W1, (size_t)(i & 31) * 512 + (i >> 5)); return; }
  i -= 512 * 32;
  if (i < 512 * 512) { w2t[i] = (f16_t)rd(W2, (size_t)(i & 511) * 512 + (i >> 9)); return; }
  i -= 512 * 512;
  if (i < NRAW_PAD * 512) {
    int n = i >> 9, k = i & 511;
    int ch = n / 24, e = n % 24;
    w3t[i] = (e < 23) ? (f16_t)rd(W3, (size_t)k * NRAW + ch * 23 + e) : (f16_t)0.0f;
    return;
  }
  i -= NRAW_PAD * 512;
  if (i < 512) { bf1[i] = rd(b1, i); return; }
  i -= 512;
  if (i < 512) { bf2[i] = rd(b2, i); return; }
  i -= 512;
  if (i < NRAW_PAD) {
    int ch = i / 24, e = i % 24;
    bf3[i] = (e < 23) ? rd(b3, (size_t)ch * 23 + e) : 0.0f;
  }
}

// Masked passthrough only: out[:, :32] = x[:, :32] (same dtype, raw copy).
__global__ void convert_x(const void* x, void* __restrict__ outv,
                          const int* flagp, int n) {
  const int flag = *flagp;
  const int i0 = (blockIdx.x * 256 + threadIdx.x) * 8;
  if (i0 >= n) return;
  const int row = i0 >> 5, col = i0 & 31;
  const size_t src = (size_t)row * 64 + col;
  if (flag) {
    const float4* s4 = (const float4*)((const float*)x + src);
    float4* d4 = (float4*)((float*)outv + src);
    d4[0] = s4[0]; d4[1] = s4[1];
  } else {
    *(uint4*)((bf16_t*)outv + src) = *(const uint4*)((const bf16_t*)x + src);
  }
}

__global__ void ld_finalize(const float* __restrict__ ldp, void* __restrict__ outv,
                            const int* __restrict__ flagp, int M) {
  const int i = blockIdx.x * 256 + threadIdx.x;
  if (i >= M) return;
  float s = 0.f;
  #pragma unroll
  for (int n = 0; n < 4; n++) s += ldp[(size_t)n * M + i];
  if (*flagp) ((float*)outv)[(size_t)M * 64 + i] = s;
  else        ((bf16_t*)outv)[(size_t)M * 64 + i] = (bf16_t)s;
}

// ---------------------------------------------------------------------------
// Fused GEMM1+GEMM2, full-dbuf 1-barrier pipeline at 512 threads:
//   Round-5's structure (As+Bs both double-buffered, ONE __syncthreads per
//   K-step) was correct but lost occupancy at 256 thr (64 KB -> 8 waves/CU).
//   At 512 thr (8 waves, 2M x 4N, wave tile 64x32): 64 KB -> 2 blocks/CU
//   = 16 waves/CU (same as round-4) WITH the better schedule.
//   Per iter k: { issue 2 glds16 Bs[nb](k+1) -> GEMM1 h(k+1) 4 MFMA (regs)
//   -> GEMM2 16 MFMA on (As[cur],Bs[cur]) -> converts + 4 ds_write As[nb]
//   -> prefetch W1/bias(k+2) -> __syncthreads }.
//   Hazards closed by __syncthreads alone: writes target buffer nb while
//   reads hit cur; nb's previous readers all passed the prior barrier;
//   the iter-end barrier publishes As[nb] (lgkmcnt) + Bs[nb] (vmcnt), both
//   covered by ~20 MFMA + converts of compute.
// ---------------------------------------------------------------------------
__launch_bounds__(512, 4)
__global__ void gemm12(const void* __restrict__ xorig, const f16_t* __restrict__ W1t,
                       const float* __restrict__ b1, const f16_t* __restrict__ W2t,
                       const float* __restrict__ b2, f16_t* __restrict__ H2,
                       int r0, const int* __restrict__ flagp) {
  constexpr int BK = 64;
  constexpr int BUF = 128 * BK;  // 8192 f16 = 16 KB per buffer
  __shared__ __align__(16) f16_t As[2 * BUF], Bs[2 * BUF];  // 64 KB
  const int t = threadIdx.x;          // 0..511
  const int id = blockIdx.x;
  const int xcd = id & 7, s = id >> 3;
  const int n0 = (s & 3) * 128;
  const int m0 = ((s >> 2) * 8 + xcd) * 128;
  const int lrow = t >> 3, lcb = t & 7;   // staging: 64 rows x 8 chunks
  const int lane = t & 63, w = t >> 6;    // 8 waves
  const int wr = (w >> 2) * 64;           // 2 M-wave rows
  const int wc = (w & 3) * 32;            // 4 N-wave cols (GEMM2)
  const int wc4 = (w & 3) * 16;           // GEMM1: 16 h1-cols per wave
  const int lm = lane & 15, quad = lane >> 4;
  const int flag = *flagp;

  // Bs staging: 2 shots/thread (rows lrow + r*64), pre-swizzled global col
  const f16_t* gb[2];
  f16_t* ldb[2];
  #pragma unroll
  for (int r = 0; r < 2; r++) {
    const int row = r * 64 + lrow;
    const int gc = (lcb ^ (row & 7)) * 8;
    gb[r] = W2t + (size_t)(n0 + row) * 512 + gc;
    ldb[r] = &Bs[row * BK + lcb * 8];
  }
  // GEMM2 fragment read offsets (elements; + cur*BUF at use)
  int apo[4][2], bpo[2][2];
  #pragma unroll
  for (int ksi = 0; ksi < 2; ksi++) {
    const int qb = ksi * 4 + quad;
    #pragma unroll
    for (int i = 0; i < 4; i++) {
      const int ra = wr + i * 16 + lm;
      apo[i][ksi] = ra * BK + ((qb ^ (ra & 7)) << 3);
    }
    #pragma unroll
    for (int j = 0; j < 2; j++) {
      const int rb = wc + j * 16 + lm;
      bpo[j][ksi] = rb * BK + ((qb ^ (rb & 7)) << 3);
    }
  }
  // X fragments (B operand of h-mfma): wave's 64 rows
  f16x8 xfr[4];
  #pragma unroll
  for (int i = 0; i < 4; i++) {
    const size_t xrow = (size_t)(r0 + m0 + wr + i * 16 + lm);
    if (flag) {
      const float* px = (const float*)xorig + xrow * 64 + quad * 8;
      const float4 a = *(const float4*)px;
      const float4 b = *(const float4*)(px + 4);
      f16x8 v;
      v[0] = (f16_t)a.x; v[1] = (f16_t)a.y; v[2] = (f16_t)a.z; v[3] = (f16_t)a.w;
      v[4] = (f16_t)b.x; v[5] = (f16_t)b.y; v[6] = (f16_t)b.z; v[7] = (f16_t)b.w;
      xfr[i] = v;
    } else {
      const bf16_t* px = (const bf16_t*)xorig + xrow * 64 + quad * 8;
      f16x8 v;
      #pragma unroll
      for (int j = 0; j < 8; j++) v[j] = (f16_t)(float)px[j];
      xfr[i] = v;
    }
  }
  // W1 A-frag pointer (h1col = kc*64 + wc4 + lm, k = quad*8+j) + bias ptr
  const f16_t* w1p = W1t + (size_t)(wc4 + lm) * 32 + quad * 8;
  const float* b1p = b1 + wc4 + 4 * quad;
  // As write offsets (local col c = wc4 + quad*4, swizzled; + nb*BUF at use)
  int woff[4];
  {
    const int cb = (w & 3) * 2 + (quad >> 1);
    #pragma unroll
    for (int i = 0; i < 4; i++) {
      const int row = wr + i * 16 + lm;
      woff[i] = row * BK + ((cb ^ (row & 7)) << 3) + 4 * (quad & 1);
    }
  }

  f32x4 acc[4][2] = {};

  // ---- prologue: stage Bs[0]; h(0) -> As[0]; preload W1/bias for h(1) ----
  #pragma unroll
  for (int r = 0; r < 2; r++) glds16(gb[r], ldb[r]);
  {
    const f16x8 w1f = *(const f16x8*)w1p;
    const float4 bv = *(const float4*)b1p;
    #pragma unroll
    for (int i = 0; i < 4; i++) {
      f32x4 z = {};
      const f32x4 h = __builtin_amdgcn_mfma_f32_16x16x32_f16(w1f, xfr[i], z, 0, 0, 0);
      f16x4 v;
      v[0] = (f16_t)fmaxf(h[0] + bv.x, 0.0f);
      v[1] = (f16_t)fmaxf(h[1] + bv.y, 0.0f);
      v[2] = (f16_t)fmaxf(h[2] + bv.z, 0.0f);
      v[3] = (f16_t)fmaxf(h[3] + bv.w, 0.0f);
      *(f16x4*)&As[woff[i]] = v;
    }
  }
  f16x8 w1fa = *(const f16x8*)(w1p + (size_t)64 * 32);
  float4 bva = *(const float4*)(b1p + 64);
  __syncthreads();  // publish As[0] + Bs[0]

  #pragma unroll
  for (int k = 0; k < 8; k++) {
    const int cur = k & 1, nb = cur ^ 1;
    // issue Bs[nb] staging for tile k+1 (covered by the MFMA below)
    if (k < 7) {
      #pragma unroll
      for (int r = 0; r < 2; r++)
        glds16(gb[r] + (k + 1) * 64, ldb[r] + nb * BUF);
    }
    // GEMM1: h(k+1) MFMA early (independent of GEMM2)
    f32x4 h[4];
    if (k < 7) {
      #pragma unroll
      for (int i = 0; i < 4; i++) {
        f32x4 z = {};
        h[i] = __builtin_amdgcn_mfma_f32_16x16x32_f16(w1fa, xfr[i], z, 0, 0, 0);
      }
    }
    // GEMM2 on (As[cur], Bs[cur]) -- 16 MFMA
    #pragma unroll
    for (int ksi = 0; ksi < 2; ksi++) {
      f16x8 af[4], bf[2];
      #pragma unroll
      for (int i = 0; i < 4; i++) af[i] = *(const f16x8*)&As[cur * BUF + apo[i][ksi]];
      #pragma unroll
      for (int j = 0; j < 2; j++) bf[j] = *(const f16x8*)&Bs[cur * BUF + bpo[j][ksi]];
      __builtin_amdgcn_s_setprio(1);
      #pragma unroll
      for (int i = 0; i < 4; i++)
        #pragma unroll
        for (int j = 0; j < 2; j++)
          acc[i][j] = __builtin_amdgcn_mfma_f32_16x16x32_f16(af[i], bf[j], acc[i][j], 0, 0, 0);
      __builtin_amdgcn_s_setprio(0);
    }
    if (k < 7) {
      // converts + As[nb] writes (other waves still read cur -- disjoint)
      #pragma unroll
      for (int i = 0; i < 4; i++) {
        f16x4 v;
        v[0] = (f16_t)fmaxf(h[i][0] + bva.x, 0.0f);
        v[1] = (f16_t)fmaxf(h[i][1] + bva.y, 0.0f);
        v[2] = (f16_t)fmaxf(h[i][2] + bva.z, 0.0f);
        v[3] = (f16_t)fmaxf(h[i][3] + bva.w, 0.0f);
        *(f16x4*)&As[nb * BUF + woff[i]] = v;
      }
      if (k < 6) {  // prefetch W1/bias for h(k+2)
        w1fa = *(const f16x8*)(w1p + (size_t)(k + 2) * 64 * 32);
        bva = *(const float4*)(b1p + (k + 2) * 64);
      }
      __syncthreads();  // publish As[nb] (lgkm) + Bs[nb] (vmcnt)
    }
  }
  #pragma unroll
  for (int i = 0; i < 4; i++)
    #pragma unroll
    for (int j = 0; j < 2; j++) {
      const int col = n0 + wc + j * 16 + lm;
      const float bv = b2[col];
      #pragma unroll
      for (int r = 0; r < 4; r++) {
        const int rowi = m0 + wr + i * 16 + quad * 4 + r;
        H2[(size_t)rowi * HID + col] = (f16_t)fmaxf(acc[i][j][r] + bv, 0.0f);
      }
    }
}

// ---------------------------------------------------------------------------
// Fused GEMM3 + spline, minimum-2-phase counted pipeline (verified round 4).
// ---------------------------------------------------------------------------
#define RSH 200        // rawh stride (f16)
#define SP1 0.5413248546f  // softplus(SP1) == 1

__launch_bounds__(512, 4)
__global__ void gemm3_spline(const f16_t* __restrict__ A, const f16_t* __restrict__ Bt,
                             const float* __restrict__ bias,
                             const void* __restrict__ xorig,
                             void* __restrict__ outv, float* __restrict__ ldp,
                             int M, int r0, const int* __restrict__ flagp) {
  // As dbuf: 2 x 128x64, Bs dbuf: 2 x 192x64 (f16) -> 81920 B total.
  __shared__ __align__(16) f16_t lds[2 * 8192 + 2 * 12288];
  f16_t* As = lds;
  f16_t* Bs = lds + 2 * 8192;
  f16_t* rawh = lds;  // 128*200 = 25600 f16 (aliases staging, post-loop)

  const int t = threadIdx.x;          // 0..511
  const int id = blockIdx.x;
  const int xcd = id & 7, sloc = id >> 3;
  const int cpx = gridDim.x >> 3;     // grid % 8 == 0 guaranteed by launcher
  const int wg = xcd * cpx + sloc;    // bijective XCD swizzle
  const int ntile = wg & 3;           // 4 N-tiles of 192 (8 channels each)
  const int m0 = (wg >> 2) * 128;
  const int n0 = ntile * 192;
  const int lane = t & 63, w = t >> 6;
  const int lm = lane & 15, quad = lane >> 4;
  const int wrow = (w >> 2) * 64, wcol = (w & 3) * 48;  // 2M x 4N wave grid
  const int lrow = t >> 3, lcb = t & 7;  // staging coords (64 rows x 8 chunks)
  const int flag = *flagp;

  // ---- staging: pre-swizzled global src, linear (swizzle-slot) LDS dest ----
  const int gc = (lcb ^ (lrow & 7)) * 8;
  const f16_t* gA = A + (size_t)(m0 + lrow) * 512 + gc;
  const f16_t* gB = Bt + (size_t)(n0 + lrow) * 512 + gc;
  f16_t* ldA = As + lrow * 64 + lcb * 8;   // rows lrow + r*64, r<2
  f16_t* ldB = Bs + lrow * 64 + lcb * 8;   // rows lrow + r*64, r<3

  // ---- fragment read offsets (elements; ksi=1 toggles ^32) ----
  int aoff[4], boff[3];
  #pragma unroll
  for (int i = 0; i < 4; i++) {
    const int ra = wrow + i * 16 + lm;
    aoff[i] = ra * 64 + ((quad ^ (ra & 7)) << 3);
  }
  #pragma unroll
  for (int j = 0; j < 3; j++) {
    const int rb = wcol + j * 16 + lm;
    boff[j] = rb * 64 + ((quad ^ (rb & 7)) << 3);
  }

  // spline inputs + bias (register prefetch, no LDS interaction)
  const int prow = t >> 3, pch = t & 7;
  float xt_pre[2];
  #pragma unroll
  for (int e = 0; e < 2; e++) {
    const size_t gi = (size_t)(r0 + m0 + e * 64 + prow) * 64 + 32 + ntile * 8 + pch;
    xt_pre[e] = flag ? ((const float*)xorig)[gi] : (float)((const bf16_t*)xorig)[gi];
  }
  float bv3[3];
  #pragma unroll
  for (int j = 0; j < 3; j++) bv3[j] = bias[n0 + wcol + j * 16 + lm];

  // ---- prologue: stage tile 0 into buf 0 ----
  #pragma unroll
  for (int r = 0; r < 2; r++) glds16(gA + r * 32768, ldA + r * 4096);
  #pragma unroll
  for (int r = 0; r < 3; r++) glds16(gB + r * 32768, ldB + r * 4096);
  __syncthreads();

  f32x4 acc[4][3] = {};

  #pragma unroll
  for (int t8 = 0; t8 < 8; t8++) {
    const f16_t* Ab = As + (t8 & 1) * 8192;
    const f16_t* Bb = Bs + (t8 & 1) * 12288;
    // issue next tile's staging EARLY -- the rest of this tile's ds_read +
    // MFMA covers the load latency; drained by the tile-end __syncthreads.
    if (t8 < 7) {
      const int nb = (t8 + 1) & 1;
      #pragma unroll
      for (int r = 0; r < 2; r++)
        glds16(gA + r * 32768 + (t8 + 1) * 64, ldA + nb * 8192 + r * 4096);
      #pragma unroll
      for (int r = 0; r < 3; r++)
        glds16(gB + r * 32768 + (t8 + 1) * 64, ldB + nb * 12288 + r * 4096);
    }
    #pragma unroll
    for (int ksi = 0; ksi < 2; ksi++) {
      f16x8 af[4], bf[3];
      #pragma unroll
      for (int i = 0; i < 4; i++)
        af[i] = *(const f16x8*)(Ab + (aoff[i] ^ (ksi << 5)));
      #pragma unroll
      for (int j = 0; j < 3; j++)
        bf[j] = *(const f16x8*)(Bb + (boff[j] ^ (ksi << 5)));
      __builtin_amdgcn_s_setprio(1);
      #pragma unroll
      for (int i = 0; i < 4; i++)
        #pragma unroll
        for (int j = 0; j < 3; j++)
          acc[i][j] = __builtin_amdgcn_mfma_f32_16x16x32_f16(af[i], bf[j], acc[i][j], 0, 0, 0);
      __builtin_amdgcn_s_setprio(0);
    }
    __syncthreads();   // drains this wave's ds_reads + ALL glds16 (vmcnt 0);
                       // publishes buf^1 for next tile across all waves
  }

  // ---- epilogue: acc+bias -> rawh LDS (staging reads all done) ----
  #pragma unroll
  for (int i = 0; i < 4; i++)
    #pragma unroll
    for (int j = 0; j < 3; j++) {
      const int col = wcol + j * 16 + lm;
      #pragma unroll
      for (int r = 0; r < 4; r++)
        rawh[(wrow + i * 16 + quad * 4 + r) * RSH + col] = (f16_t)(acc[i][j][r] + bv3[j]);
    }
  __syncthreads();

  // ---- spline: 2 (row, channel) pairs per thread ----
  #pragma unroll
  for (int e = 0; e < 2; e++) {
    const int row = e * 64 + prow;
    const f16_t* c16 = &rawh[row * RSH + pch * 24];
    const f16x8 v0 = *(const f16x8*)(c16);
    const f16x8 v1 = *(const f16x8*)(c16 + 8);
    const f16x8 v2 = *(const f16x8*)(c16 + 16);
    float wa[8], ha[8], da[7];
    #pragma unroll
    for (int j = 0; j < 8; j++) { wa[j] = (float)v0[j]; ha[j] = (float)v1[j]; }
    #pragma unroll
    for (int j = 0; j < 7; j++) da[j] = (float)v2[j];

    const float xt = xt_pre[e];
    const bool inside = (xt >= -TAILB) && (xt <= TAILB);
    const float xc = fminf(fmaxf(xt, -TAILB + 1e-6f), TAILB - 1e-6f);

    float mw = wa[0], mh = ha[0];
    #pragma unroll
    for (int j = 1; j < 8; j++) { mw = fmaxf(mw, wa[j]); mh = fmaxf(mh, ha[j]); }
    float ew[8], eh[8], sew = 0.f, seh = 0.f;
    #pragma unroll
    for (int j = 0; j < 8; j++) {
      ew[j] = __expf(wa[j] - mw); sew += ew[j];
      eh[j] = __expf(ha[j] - mh); seh += eh[j];
    }
    const float wsc = 6.0f * frcp(sew), hsc = 6.0f * frcp(seh);
    #pragma unroll
    for (int j = 0; j < 8; j++) { ew[j] *= wsc; eh[j] *= hsc; }

    float accw = -TAILB, runh = -TAILB;
    float cwk = -TAILB, chk = -TAILB;
    float wk = ew[0], hk = eh[0];
    float dkr = SP1, dk1r = da[0];
    #pragma unroll
    for (int i = 0; i < 7; i++) {
      accw += ew[i];
      runh += eh[i];
      const bool cond = accw < xc;
      cwk  = cond ? accw : cwk;
      chk  = cond ? runh : chk;
      wk   = cond ? ew[i + 1] : wk;
      hk   = cond ? eh[i + 1] : hk;
      dkr  = cond ? da[i] : dkr;
      dk1r = cond ? ((i == 6) ? SP1 : da[i + 1]) : dk1r;
    }
    const float dk  = fmaxf(dkr, 0.0f)  + __logf(1.0f + __expf(-fabsf(dkr)));
    const float dk1 = fmaxf(dk1r, 0.0f) + __logf(1.0f + __expf(-fabsf(dk1r)));

    const float rwk = frcp(wk);
    float xi = (xc - cwk) * rwk;
    xi = fminf(fmaxf(xi, 1e-6f), 1.0f - 1e-6f);
    const float om = 1.0f - xi;
    const float sl = hk * rwk;
    const float num = hk * (sl * xi * xi + dk * xi * om);
    const float den = sl + (dk + dk1 - 2.0f * sl) * xi * om;
    const float y_in = chk + num * frcp(den);
    const float t1 = sl * sl * (dk1 * xi * xi + 2.0f * sl * xi * om + dk * om * om);
    const float ld_in = __logf(t1 + 1e-8f) - __logf(den * den + 1e-8f);

    const float yv = inside ? y_in : xt;
    const float ldv = inside ? ld_in : 0.0f;

    const size_t grow = (size_t)(r0 + m0 + row);
    if (flag) ((float*)outv)[grow * 64 + 32 + ntile * 8 + pch] = yv;
    else      ((bf16_t*)outv)[grow * 64 + 32 + ntile * 8 + pch] = (bf16_t)yv;

    float l = ldv + __shfl_down(ldv, 1, 8);
    l += __shfl_down(l, 2, 8);
    l += __shfl_down(l, 4, 8);
    if ((t & 7) == 0) ldp[(size_t)ntile * M + grow] = l;
  }
}

// ---------------------------------------------------------------------------
extern "C" void kernel_launch(void* const* d_in, const int* in_sizes, int n_in,
                              void* d_out, int out_size, void* d_ws, size_t ws_size,
                              hipStream_t stream) {
  const void* x  = d_in[0];
  const void* W1 = d_in[1];
  const void* b1 = d_in[2];
  const void* W2 = d_in[3];
  const void* b2 = d_in[4];
  const void* W3 = d_in[5];
  const void* b3 = d_in[6];
  const int M = in_sizes[0] / 64;  // 131072

  char* ws = (char*)d_ws;
  size_t off = 0;
  auto alloc = [&](size_t bytes) {
    void* p = ws + off;
    off += (bytes + 255) & ~(size_t)255;
    return p;
  };
  int*   flag = (int*)alloc(256);
  float* bf1  = (float*)alloc(512 * 4);
  float* bf2  = (float*)alloc(512 * 4);
  float* bf3  = (float*)alloc(NRAW_PAD * 4);
  f16_t* W1t  = (f16_t*)alloc((size_t)512 * 32 * 2);
  f16_t* W2t  = (f16_t*)alloc((size_t)512 * 512 * 2);
  f16_t* W3t  = (f16_t*)alloc((size_t)NRAW_PAD * 512 * 2);
  float* ldp  = (float*)alloc((size_t)8 * M * 4);

  const size_t per_row = (size_t)HID * 2;
  size_t avail = (ws_size > off + 4096) ? (ws_size - off - 4096) : 0;
  long rows = (long)(avail / per_row);
  rows -= rows % 1024;
  if (rows > M) rows = M;
  if (rows < 1024) rows = 1024;

  f16_t* h2 = (f16_t*)alloc((size_t)rows * HID * 2);

  detect_dtype<<<1, 256, 0, stream>>>(x, flag);
  conv_wb<<<2631, 256, 0, stream>>>(W1, W2, W3, b1, b2, b3,
                                    W1t, W2t, W3t, bf1, bf2, bf3, flag);
  convert_x<<<(M * 32 / 8 + 255) / 256, 256, 0, stream>>>(x, d_out, flag, M * 32);

  for (int r0 = 0; r0 < M; r0 += (int)rows) {
    const int mc = (int)((M - r0 < rows) ? (M - r0) : rows);
    const int mt128 = mc / 128;
    gemm12<<<mt128 * 4, 512, 0, stream>>>(x, W1t, bf1, W2t, bf2, h2, r0, flag);
    gemm3_spline<<<mt128 * 4, 512, 0, stream>>>(
        h2, W3t, bf3, x, d_out, ldp, M, r0, flag);
  }
  ld_finalize<<<(M + 255) / 256, 256, 0, stream>>>(ldp, d_out, flag, M);
}